// Round 1
// baseline (227.768 us; speedup 1.0000x reference)
//
#include <hip/hip_runtime.h>
#include <hip/hip_bf16.h>
#include <math.h>

#define GN 12288
#define GE 196608
#define GK 1433
#define GC 32
#define KSPLIT 4
#define KCHUNK 359  // ceil(1433/4)

// ---------------- zero ----------------
__global__ void zero_kernel(unsigned* __restrict__ p, int n) {
    int i = blockIdx.x * blockDim.x + threadIdx.x;
    if (i < n) p[i] = 0u;
}

// ---------------- edge degree/count ----------------
__global__ void count_kernel(const int* __restrict__ ei,
                             unsigned* __restrict__ deg,  // in-degree (dst) count, excl self-loop
                             unsigned* __restrict__ cnt)  // out-edge (src) count
{
    int e = blockIdx.x * blockDim.x + threadIdx.x;
    if (e < GE) {
        atomicAdd(&cnt[ei[e]], 1u);        // src = edge_index[0][e]
        atomicAdd(&deg[ei[GE + e]], 1u);   // dst = edge_index[1][e]
    }
}

// ---------------- prefix sum (single block, 1024 threads x 12 elems) ----------------
__global__ __launch_bounds__(1024) void prefix_kernel(const unsigned* __restrict__ cnt,
                                                      unsigned* __restrict__ offs) {
    __shared__ unsigned sc[1024];
    int t = threadIdx.x;
    unsigned loc[12];
    unsigned s = 0;
    #pragma unroll
    for (int j = 0; j < 12; ++j) { loc[j] = cnt[t * 12 + j]; s += loc[j]; }
    sc[t] = s;
    __syncthreads();
    unsigned mysum = s;
    for (int d = 1; d < 1024; d <<= 1) {
        unsigned v = (t >= d) ? sc[t - d] : 0u;
        __syncthreads();
        sc[t] += v;
        __syncthreads();
    }
    unsigned run = sc[t] - mysum;  // exclusive prefix of this thread's chunk
    #pragma unroll
    for (int j = 0; j < 12; ++j) { offs[t * 12 + j] = run; run += loc[j]; }
}

// ---------------- scatter into CSR ----------------
__global__ void scatter_kernel(const int* __restrict__ ei,
                               const unsigned* __restrict__ offs,
                               unsigned* __restrict__ cursor,
                               unsigned* __restrict__ adj) {
    int e = blockIdx.x * blockDim.x + threadIdx.x;
    if (e < GE) {
        int src = ei[e];
        unsigned pos = atomicAdd(&cursor[src], 1u);
        adj[offs[src] + pos] = (unsigned)ei[GE + e];
    }
}

// ---------------- GEMM: partial[ks] = x[:, kslice] @ W1[kslice, :] ----------------
// BM=64 rows, 32 cols, BK=32, 256 threads, each thread 2 rows x 4 cols.
__global__ __launch_bounds__(256) void gemm_kernel(const float* __restrict__ x,
                                                   const float* __restrict__ W1,
                                                   float* __restrict__ partial) {
    __shared__ float xs[64][36];  // +4 pad: breaks row-stride bank aliasing
    __shared__ float ws[32][32];
    int t = threadIdx.x;
    int row0 = blockIdx.x * 64;
    int ks = blockIdx.y;
    int k0 = ks * KCHUNK;
    int kend = min(GK, k0 + KCHUNK);
    int cg = (t & 7) * 4;
    int rg = (t >> 3) * 2;
    float a00 = 0.f, a01 = 0.f, a02 = 0.f, a03 = 0.f;
    float a10 = 0.f, a11 = 0.f, a12 = 0.f, a13 = 0.f;

    for (int kb = k0; kb < kend; kb += 32) {
        #pragma unroll
        for (int l = 0; l < 8; ++l) {
            int idx = t + l * 256;
            int r = idx >> 5, kk = idx & 31;
            int k = kb + kk;
            xs[r][kk] = (k < kend) ? x[(size_t)(row0 + r) * GK + k] : 0.f;
        }
        #pragma unroll
        for (int l = 0; l < 4; ++l) {
            int idx = t + l * 256;
            int kk = idx >> 5, c = idx & 31;
            int k = kb + kk;
            ws[kk][c] = (k < kend) ? W1[(size_t)k * GC + c] : 0.f;
        }
        __syncthreads();
        #pragma unroll
        for (int kk = 0; kk < 32; kk += 4) {
            float4 xa = *(const float4*)&xs[rg][kk];
            float4 xb = *(const float4*)&xs[rg + 1][kk];
            float4 w0 = *(const float4*)&ws[kk][cg];
            float4 w1 = *(const float4*)&ws[kk + 1][cg];
            float4 w2 = *(const float4*)&ws[kk + 2][cg];
            float4 w3 = *(const float4*)&ws[kk + 3][cg];
            a00 += xa.x * w0.x + xa.y * w1.x + xa.z * w2.x + xa.w * w3.x;
            a01 += xa.x * w0.y + xa.y * w1.y + xa.z * w2.y + xa.w * w3.y;
            a02 += xa.x * w0.z + xa.y * w1.z + xa.z * w2.z + xa.w * w3.z;
            a03 += xa.x * w0.w + xa.y * w1.w + xa.z * w2.w + xa.w * w3.w;
            a10 += xb.x * w0.x + xb.y * w1.x + xb.z * w2.x + xb.w * w3.x;
            a11 += xb.x * w0.y + xb.y * w1.y + xb.z * w2.y + xb.w * w3.y;
            a12 += xb.x * w0.z + xb.y * w1.z + xb.z * w2.z + xb.w * w3.z;
            a13 += xb.x * w0.w + xb.y * w1.w + xb.z * w2.w + xb.w * w3.w;
        }
        __syncthreads();
    }
    size_t base = ((size_t)ks * GN + row0 + rg) * GC + cg;
    *(float4*)&partial[base] = make_float4(a00, a01, a02, a03);
    *(float4*)&partial[base + GC] = make_float4(a10, a11, a12, a13);
}

// ---------------- reduce K-splits ----------------
__global__ void reduce_kernel(const float* __restrict__ partial, float* __restrict__ xw) {
    int i = blockIdx.x * blockDim.x + threadIdx.x;
    const size_t S = (size_t)GN * GC;
    xw[i] = partial[i] + partial[S + i] + partial[2 * S + i] + partial[3 * S + i];
}

// ---------------- GCN gather: h = relu(b1 + dis_i*(dis_i*xw_i + sum dis_dst*xw_dst)) ----------------
__global__ __launch_bounds__(256) void gcn_kernel(const float* __restrict__ xw,
                                                  const unsigned* __restrict__ deg,
                                                  const unsigned* __restrict__ cnt,
                                                  const unsigned* __restrict__ offs,
                                                  const unsigned* __restrict__ adj,
                                                  const float* __restrict__ b1,
                                                  float* __restrict__ h) {
    int w = threadIdx.x >> 6;
    int lane = threadIdx.x & 63;
    int i = blockIdx.x * 4 + w;
    int f = lane & 31, half = lane >> 5;
    unsigned ci = cnt[i], oi = offs[i];
    float acc = 0.f;
    for (unsigned j = half; j < ci; j += 2) {
        unsigned dst = adj[oi + j];
        float disd = 1.0f / sqrtf((float)(deg[dst] + 1u));
        acc += xw[(size_t)dst * GC + f] * disd;
    }
    acc += __shfl_xor(acc, 32, 64);
    float disi = 1.0f / sqrtf((float)(deg[i] + 1u));
    float v = b1[f] + disi * (disi * xw[(size_t)i * GC + f] + acc);
    if (half == 0) h[(size_t)i * GC + f] = fmaxf(v, 0.f);
}

// ---------------- SAGE gather + fused head ----------------
__global__ __launch_bounds__(256) void sage_kernel(const float* __restrict__ h,
                                                   const unsigned* __restrict__ cnt,
                                                   const unsigned* __restrict__ offs,
                                                   const unsigned* __restrict__ adj,
                                                   const float* __restrict__ Wl,
                                                   const float* __restrict__ bl,
                                                   const float* __restrict__ Wr,
                                                   const float* __restrict__ br,
                                                   const float* __restrict__ W3,
                                                   const float* __restrict__ b3,
                                                   float* __restrict__ out) {
    __shared__ float sh[4][64];
    __shared__ float so[4][16];
    int w = threadIdx.x >> 6, lane = threadIdx.x & 63;
    int i = blockIdx.x * 4 + w;
    int f = lane & 31, half = lane >> 5;
    unsigned ci = cnt[i], oi = offs[i];
    float acc = 0.f;
    for (unsigned j = half; j < ci; j += 2) acc += h[(size_t)adj[oi + j] * GC + f];
    acc += __shfl_xor(acc, 32, 64);
    float agg = ci ? acc / (float)ci : 0.f;
    float hv = h[(size_t)i * GC + f];
    if (half == 0) { sh[w][f] = hv; sh[w][32 + f] = agg; }
    __syncthreads();
    int c = lane;
    float hid = 0.f;
    if (c < 16) {
        hid = bl[c] + br[c];
        #pragma unroll
        for (int ff = 0; ff < 32; ++ff)
            hid += sh[w][ff] * Wl[ff * 16 + c] + sh[w][32 + ff] * Wr[ff * 16 + c];
        hid = fmaxf(hid, 0.f);
    }
    float n2 = hid * hid;
    n2 += __shfl_xor(n2, 1, 64);
    n2 += __shfl_xor(n2, 2, 64);
    n2 += __shfl_xor(n2, 4, 64);
    n2 += __shfl_xor(n2, 8, 64);
    float o = hid / (sqrtf(n2) + 1e-6f);
    if (c < 16) so[w][c] = o;
    __syncthreads();
    float logit = -INFINITY;
    if (lane < 7) {
        logit = b3[lane];
        #pragma unroll
        for (int cc = 0; cc < 16; ++cc) logit += so[w][cc] * W3[cc * 7 + lane];
    }
    float m = logit;
    m = fmaxf(m, __shfl_xor(m, 1, 64));
    m = fmaxf(m, __shfl_xor(m, 2, 64));
    m = fmaxf(m, __shfl_xor(m, 4, 64));
    float e = expf(logit - m);
    float s = e;
    s += __shfl_xor(s, 1, 64);
    s += __shfl_xor(s, 2, 64);
    s += __shfl_xor(s, 4, 64);
    if (lane < 7) out[(size_t)i * 7 + lane] = e / s;
}

extern "C" void kernel_launch(void* const* d_in, const int* in_sizes, int n_in,
                              void* d_out, int out_size, void* d_ws, size_t ws_size,
                              hipStream_t stream) {
    const float* x  = (const float*)d_in[0];
    const int*   ei = (const int*)d_in[1];
    const float* W1 = (const float*)d_in[2];
    const float* b1 = (const float*)d_in[3];
    const float* Wl = (const float*)d_in[4];
    const float* bl = (const float*)d_in[5];
    const float* Wr = (const float*)d_in[6];
    const float* br = (const float*)d_in[7];
    const float* W3 = (const float*)d_in[8];
    const float* b3 = (const float*)d_in[9];
    float* out = (float*)d_out;

    char* ws = (char*)d_ws;
    // layout (bytes):
    float*    partial = (float*)(ws);                       // KSPLIT*N*32*4 = 6291456
    float*    xw      = (float*)(ws + 6291456);             // N*32*4 = 1572864
    float*    h       = (float*)(ws + 7864320);             // N*32*4 = 1572864
    unsigned* deg     = (unsigned*)(ws + 9437184);          // N*4
    unsigned* cnt     = deg + GN;
    unsigned* cursor  = cnt + GN;
    unsigned* offs    = cursor + GN;
    unsigned* adj     = offs + GN;                          // E*4

    // 1. zero deg/cnt/cursor (contiguous 3N words)
    zero_kernel<<<(3 * GN + 255) / 256, 256, 0, stream>>>(deg, 3 * GN);
    // 2. degree + out-count
    count_kernel<<<GE / 256, 256, 0, stream>>>(ei, deg, cnt);
    // 3. CSR offsets
    prefix_kernel<<<1, 1024, 0, stream>>>(cnt, offs);
    // 4. CSR adjacency
    scatter_kernel<<<GE / 256, 256, 0, stream>>>(ei, offs, cursor, adj);
    // 5. xw partials = x @ W1  (k-split 4)
    gemm_kernel<<<dim3(GN / 64, KSPLIT), 256, 0, stream>>>(x, W1, partial);
    // 6. reduce partials
    reduce_kernel<<<(GN * GC) / 256, 256, 0, stream>>>(partial, xw);
    // 7. GCN layer -> h
    gcn_kernel<<<GN / 4, 256, 0, stream>>>(xw, deg, cnt, offs, adj, b1, h);
    // 8. SAGE + head -> out
    sage_kernel<<<GN / 4, 256, 0, stream>>>(h, cnt, offs, adj, Wl, bl, Wr, br, W3, b3, out);
}